// Round 6
// baseline (396.522 us; speedup 1.0000x reference)
//
#include <hip/hip_runtime.h>
#include <hip/hip_bf16.h>
#include <cstddef>
#include <cstdint>

typedef __attribute__((ext_vector_type(8))) short short8_t;   // 8 bf16 (4 VGPRs)
typedef __attribute__((ext_vector_type(4))) float f32x4;
typedef __attribute__((ext_vector_type(2))) float f32x2;
typedef unsigned short ushort4a __attribute__((ext_vector_type(4))); // 8B

// Per-wave fences: forbid compiler motion of memory ops and drain the HW
// queue. Cross-lane LDS deps and LDS-DMA writes are invisible to per-thread
// dependence analysis.
#define WAVE_FENCE()                                        \
  do {                                                      \
    asm volatile("s_waitcnt lgkmcnt(0)" ::: "memory");      \
    __builtin_amdgcn_sched_barrier(0);                      \
  } while (0)
#define VM_FENCE()                                          \
  do {                                                      \
    asm volatile("s_waitcnt vmcnt(0)" ::: "memory");        \
    __builtin_amdgcn_sched_barrier(0);                      \
  } while (0)

namespace {
constexpr int T = 2048;
constexpr int NB = 16;
constexpr int NJ = 53;
constexpr int NN = 18;              // names
constexpr int TTILE = 256;          // R16: per-block tax amortization; NT stores keep L2 reuse
constexpr int NTILES = T / TTILE;   // 8
constexpr int WROWS = TTILE / 4;    // 64 out rows per wave (contiguous chunk)
constexpr int CT_W = WROWS / 16;    // 4 conv tiles per wave
constexpr int MT_W = CT_W + 1;      // 5 lin tiles per wave (shifted base R0-1)
constexpr int HSTR = 36;            // ushort stride per h row (72B)
constexpr int HSLOT = 16 * HSTR;    // 576 ushorts = 1152B per ring slot
// SSTR=38 (R15): g-stride 152B == 24 mod 32 dwords -> staging writes 2-way (free).
constexpr int SSTR = 38;            // f32 stride of store-staging tile (152B)
// Per-wave LDS region: feat 4096 | h ring 2x1152=2304 | staging 2432 = 8832B
constexpr int WBYTES = 4096 + 2 * 1152 + 2432;   // 8832
constexpr int NBLK = NB * NJ * NTILES;  // 6784
constexpr int XSPAN = NBLK / 8;         // 848 (bijective XCD swizzle)
}

__constant__ int c_name_ids[NJ] = {
    0,1,2,3,4,1,2,3,4,5,6,7,8,9,10,11,12,13,14,15,16,14,15,16,14,15,16,
    14,15,16,14,15,16,10,11,12,13,14,15,16,14,15,16,14,15,16,14,15,16,
    14,15,16,17};

// Precomputed weight fragments: [name][ks|k][nt][hi/lo][lane]
__device__ short8_t g_linfrag[NN][2][2][2][64];   // 147 KB
__device__ short8_t g_convfrag[NN][3][2][2][64];  // 221 KB

__device__ __forceinline__ unsigned short f2bf(float f) {
  return __builtin_bit_cast(unsigned short, __float2bfloat16(f));
}
__device__ __forceinline__ float bf2f(unsigned short u) {
  return __bfloat162float(__builtin_bit_cast(__hip_bfloat16, u));
}

// slot map: slot(g,e) -> k = 4g + (e&3) + 16*(e>>2); used identically for A and B
// fragments, so any true HW k-map yields a correct dot product.

__global__ __launch_bounds__(64)
void prep_weights(const float* __restrict__ lin_w,
                  const float* __restrict__ conv_w)
{
  const int n = blockIdx.x;
  const int l = threadIdx.x;
  const int r = l & 15;
  const int g = l >> 4;
#pragma unroll
  for (int ks = 0; ks < 2; ++ks)
#pragma unroll
    for (int nt = 0; nt < 2; ++nt) {
      short8_t hi8, lo8;
#pragma unroll
      for (int e = 0; e < 8; ++e) {
        const int kk = 4 * g + (e & 3) + 16 * (e >> 2);
        const float w = lin_w[((size_t)n * 64 + ks * 32 + kk) * 32 + r + 16 * nt];
        const unsigned short h = f2bf(w);
        hi8[e] = (short)h;
        lo8[e] = (short)f2bf(w - bf2f(h));
      }
      g_linfrag[n][ks][nt][0][l] = hi8;
      g_linfrag[n][ks][nt][1][l] = lo8;
    }
#pragma unroll
  for (int k = 0; k < 3; ++k)
#pragma unroll
    for (int nt = 0; nt < 2; ++nt) {
      short8_t hi8, lo8;
#pragma unroll
      for (int e = 0; e < 8; ++e) {
        const int i = 4 * g + (e & 3) + 16 * (e >> 2);
        const float w = conv_w[(((size_t)n * 32 + r + 16 * nt) * 32 + i) * 3 + k];
        const unsigned short h = f2bf(w);
        hi8[e] = (short)h;
        lo8[e] = (short)f2bf(w - bf2f(h));
      }
      g_convfrag[n][k][nt][0][l] = hi8;
      g_convfrag[n][k][nt][1][l] = lo8;
    }
}

// R18: FUSED per-wave lin+conv with a rolling h window. Each wave owns 64
// contiguous out rows; lin tile i covers padded-time rows [R0-1+16i,
// R0+15+16i) into a 2-slot wave-private h ring; conv tile i-1 (needs h rows
// up to R0+16i) runs immediately after lin tile i in the SAME iteration.
//   - __syncthreads deleted entirely (boundary h rows recomputed: 20 vs 17
//     lin tiles/block, +18% lin MFMA at MfmaUtil=13% -- cheap)
//   - issue_feat(i+1) now has an entire conv tile of work before the next
//     VM_FENCE -> the per-iteration vmcnt(0) drain is covered (~4x more
//     latency cover than R16's lin-only iteration)
//   - LDS 35,328B (= R16) -> same 4 blocks/CU; numerics identical to R16.
// Transport stays LDS-DMA (R17 proved direct global->VGPR loads lose ~13us:
// scattered 64B/row loads on the wave's own vmcnt critical path).
__global__ __launch_bounds__(256, 4)
void fused_rcb_mfma(const float* __restrict__ x,
                    const float* __restrict__ lin_b,
                    const float* __restrict__ conv_b,
                    float* __restrict__ out)
{
  __shared__ __align__(16) char s_mem[4][WBYTES];   // 35,328B

  const int raw = blockIdx.x;
  const int bid = (raw % 8) * XSPAN + (raw / 8);   // bijective XCD swizzle
  const int j    = bid % NJ;
  const int tile = (bid / NJ) % NTILES;
  const int b    = bid / (NJ * NTILES);
  const int nid  = c_name_ids[j];
  const int jp   = (j > 0) ? (j - 1) : 0;
  const int t0   = tile * TTILE;

  const int tid = threadIdx.x;
  const int wv = tid >> 6;        // wave 0..3
  const int l  = tid & 63;
  const int r  = l & 15;          // M/N index within fragment
  const int g  = l >> 4;          // k-slot group

  char*           featc = s_mem[wv];                                   // 4096B
  unsigned short* s_h   = reinterpret_cast<unsigned short*>(s_mem[wv] + 4096); // 2304B
  float*          st    = reinterpret_cast<float*>(s_mem[wv] + 4096 + 2304);   // 2432B

  const int R0 = t0 + wv * WROWS;   // wave's first out row (global time)

  const float* xj_base = x + ((size_t)b * T * NJ + j) * 32;
  const float* xp_base = x + ((size_t)b * T * NJ + jp) * 32;

  // ---- weight fragments: coalesced 16B/lane loads from prep tables.
  // Both lin and conv weights loaded up front (conv is consumed every
  // iteration now); VGPR ~90 < 128 cap of launch_bounds(256,4).
  short8_t blh[2][2], bll[2][2];
#pragma unroll
  for (int ks = 0; ks < 2; ++ks)
#pragma unroll
    for (int nt = 0; nt < 2; ++nt) {
      blh[ks][nt] = g_linfrag[nid][ks][nt][0][l];
      bll[ks][nt] = g_linfrag[nid][ks][nt][1][l];
    }
  short8_t bch[3][2], bcl[3][2];
#pragma unroll
  for (int k = 0; k < 3; ++k)
#pragma unroll
    for (int nt = 0; nt < 2; ++nt) {
      bch[k][nt] = g_convfrag[nid][k][nt][0][l];
      bcl[k][nt] = g_convfrag[nid][k][nt][1][l];
    }
  const float lb0 = lin_b[nid * 32 + r];
  const float lb1 = lin_b[nid * 32 + r + 16];
  const float cb0 = conv_b[nid * 32 + r];
  const float cb1 = conv_b[nid * 32 + r + 16];

  // Issue the 4 LDS-DMA loads for lin tile i: 2 j x 2 groups of 8 rows, each
  // instruction a contiguous 1KB (8 full lines). Global source byte is
  // inverse-XOR-swizzled so LDS holds the swizzled layout (rule #21).
  auto issue_feat = [&](int i) {
#pragma unroll
    for (int j2 = 0; j2 < 2; ++j2) {
      const float* jb = j2 ? xp_base : xj_base;
#pragma unroll
      for (int hg = 0; hg < 2; ++hg) {
        const int row = hg * 8 + (l >> 3);
        int t = R0 - 1 + i * 16 + row;        // shifted tile base; reflect pad
        if (t < 0) t = -t;
        if (t > T - 1) t = 2 * (T - 1) - t;
        const char* src = reinterpret_cast<const char*>(jb + (size_t)t * (NJ * 32))
                          + (((l & 7) * 16) ^ ((row & 7) << 4));
        __builtin_amdgcn_global_load_lds(
            (const __attribute__((address_space(1))) unsigned int*)src,
            (__attribute__((address_space(3))) unsigned int*)(&featc[j2 * 2048 + hg * 1024]),
            16, 0, 0);
      }
    }
  };

  // Lin tile i: fragments from featc, MFMA, h -> ring slot (i&1).
  // Returns after issuing next DMA (caller passes whether to).
  auto lin_tile = [&](int i) {
    VM_FENCE();   // feat tile i fully landed in LDS (LDS-DMA tracked by vmcnt)

    f32x4 a0[2], a1[2];
#pragma unroll
    for (int ks = 0; ks < 2; ++ks) {
      const char* fw = featc + ks * 2048 + r * 128;
      a0[ks] = *reinterpret_cast<const f32x4*>(fw + ((16 * g) ^ ((r & 7) << 4)));
      a1[ks] = *reinterpret_cast<const f32x4*>(fw + ((64 + 16 * g) ^ ((r & 7) << 4)));
    }
    WAVE_FENCE();                       // feat reads retired -> buffer reusable
    if (i + 1 < MT_W) issue_feat(i + 1); // DMA overlaps cvt+MFMA AND conv below

    short8_t ah[2], al[2];
#pragma unroll
    for (int ks = 0; ks < 2; ++ks) {
#pragma unroll
      for (int e = 0; e < 8; ++e) {
        const float f = (e < 4) ? a0[ks][e] : a1[ks][e - 4];
        const uint32_t bi = __builtin_bit_cast(uint32_t, f);
        ah[ks][e] = (short)(unsigned short)(bi >> 16);                    // hi = RTZ top16
        const float lo = f - __builtin_bit_cast(float, bi & 0xffff0000u); // exact residual
        al[ks][e] = (short)(unsigned short)(__builtin_bit_cast(uint32_t, lo) >> 16); // RTZ
      }
    }

    unsigned short* hs = s_h + (i & 1) * HSLOT;
#pragma unroll
    for (int nt = 0; nt < 2; ++nt) {
      const float lb = nt ? lb1 : lb0;
      f32x4 acc = {lb, lb, lb, lb};
#pragma unroll
      for (int ks = 0; ks < 2; ++ks) {
        acc = __builtin_amdgcn_mfma_f32_16x16x32_bf16(ah[ks], blh[ks][nt], acc, 0, 0, 0);
        acc = __builtin_amdgcn_mfma_f32_16x16x32_bf16(al[ks], blh[ks][nt], acc, 0, 0, 0);
        acc = __builtin_amdgcn_mfma_f32_16x16x32_bf16(ah[ks], bll[ks][nt], acc, 0, 0, 0);
      }
      // C/D layout (m89): row = 4g+q, col = r
#pragma unroll
      for (int q = 0; q < 4; ++q)
        hs[(4 * g + q) * HSTR + r + 16 * nt] = f2bf(fmaxf(acc[q], 0.0f));
    }
  };

  // Conv tile ct: h rows r+k span ring slots ct (rows 0..15) and ct+1 (rows 0..1).
  auto conv_tile = [&](int ct) {
    short8_t ah[3];
#pragma unroll
    for (int k = 0; k < 3; ++k) {
      const int rowpk = r + k;                               // 0..17
      const unsigned short* base =
          s_h + (((ct + (rowpk >> 4)) & 1) * HSLOT) + (rowpk & 15) * HSTR;
      const ushort4a u0 = *reinterpret_cast<const ushort4a*>(base + 4 * g);
      const ushort4a u1 = *reinterpret_cast<const ushort4a*>(base + 16 + 4 * g);
      short8_t hi8;
#pragma unroll
      for (int e = 0; e < 4; ++e) {
        hi8[e] = (short)u0[e];
        hi8[e + 4] = (short)u1[e];
      }
      ah[k] = hi8;
    }

    f32x4 accv[2];
#pragma unroll
    for (int nt = 0; nt < 2; ++nt) {
      const float cb = nt ? cb1 : cb0;
      f32x4 acc = {cb, cb, cb, cb};
#pragma unroll
      for (int k = 0; k < 3; ++k) {
        acc = __builtin_amdgcn_mfma_f32_16x16x32_bf16(ah[k], bch[k][nt], acc, 0, 0, 0);
        acc = __builtin_amdgcn_mfma_f32_16x16x32_bf16(ah[k], bcl[k][nt], acc, 0, 0, 0);
      }
      accv[nt] = acc;
    }

    // ---- wide-store epilogue: transpose acc through wave-private LDS ----
    WAVE_FENCE();   // WAR: previous tile's staging reads retired
#pragma unroll
    for (int nt = 0; nt < 2; ++nt)
#pragma unroll
      for (int q = 0; q < 4; ++q)
        st[(4 * g + q) * SSTR + r + 16 * nt] = accv[nt][q];
    WAVE_FENCE();   // RAW: staging writes visible to transposed reads

#pragma unroll
    for (int h2 = 0; h2 < 2; ++h2) {
      const int row = h2 * 8 + (l >> 3);          // 8-lane groups read one row
      const float* rp = st + row * SSTR + (l & 7) * 4;
      const f32x2 rd0 = *reinterpret_cast<const f32x2*>(rp);      // 8B reads keep
      const f32x2 rd1 = *reinterpret_cast<const f32x2*>(rp + 2);  // odd rows aligned
      f32x4 rd;
      rd[0] = rd0[0]; rd[1] = rd0[1]; rd[2] = rd1[0]; rd[3] = rd1[1];
      const int t = R0 + 16 * ct + row;
      // Nontemporal: out is write-once; do not evict the L2-resident x columns.
      __builtin_nontemporal_store(rd, reinterpret_cast<f32x4*>(
          out + ((size_t)(b * T + t) * NJ + j) * 32 + (l & 7) * 4));
    }
  };

  // ---------------- fused pipeline (no __syncthreads anywhere) ----------------
  issue_feat(0);
  lin_tile(0);                     // issues feat(1) internally
  for (int i = 1; i < MT_W; ++i) {
    lin_tile(i);                   // issues feat(i+1); DMA covers conv below
    WAVE_FENCE();                  // h writes (tiles i-1, i) visible to reads
    conv_tile(i - 1);
  }
}

extern "C" void kernel_launch(void* const* d_in, const int* in_sizes, int n_in,
                              void* d_out, int out_size, void* d_ws, size_t ws_size,
                              hipStream_t stream) {
  const float* x      = (const float*)d_in[0];
  const float* lin_w  = (const float*)d_in[1];
  const float* lin_b  = (const float*)d_in[2];
  const float* conv_w = (const float*)d_in[3];
  const float* conv_b = (const float*)d_in[4];
  float* out = (float*)d_out;

  prep_weights<<<dim3(NN), 64, 0, stream>>>(lin_w, conv_w);
  fused_rcb_mfma<<<dim3(NBLK), 256, 0, stream>>>(x, lin_b, conv_b, out);
}

// Round 7
// 157.192 us; speedup vs baseline: 2.5225x; 2.5225x over previous
//
#include <hip/hip_runtime.h>
#include <hip/hip_bf16.h>
#include <cstddef>
#include <cstdint>

typedef __attribute__((ext_vector_type(8))) short short8_t;   // 8 bf16 (4 VGPRs)
typedef __attribute__((ext_vector_type(4))) float f32x4;
typedef __attribute__((ext_vector_type(2))) float f32x2;
typedef unsigned short ushort4a __attribute__((ext_vector_type(4))); // 8B

// Per-wave fences: forbid compiler motion of memory ops and drain the HW
// queue. Cross-lane LDS deps and LDS-DMA writes are invisible to per-thread
// dependence analysis.
#define WAVE_FENCE()                                        \
  do {                                                      \
    asm volatile("s_waitcnt lgkmcnt(0)" ::: "memory");      \
    __builtin_amdgcn_sched_barrier(0);                      \
  } while (0)
#define VM_FENCE()                                          \
  do {                                                      \
    asm volatile("s_waitcnt vmcnt(0)" ::: "memory");        \
    __builtin_amdgcn_sched_barrier(0);                      \
  } while (0)

namespace {
constexpr int T = 2048;
constexpr int NB = 16;
constexpr int NJ = 53;
constexpr int NN = 18;              // names
constexpr int TTILE = 256;          // R16: per-block tax amortization; NT stores keep L2 reuse
constexpr int NTILES = T / TTILE;   // 8
constexpr int NWAVES = 8;           // R19: 512-thread blocks -> 8 waves
constexpr int MT_LIN = 17;          // ceil(258/16) m-tiles for linear phase
constexpr int MT_CNV = 16;          // conv m-tiles
constexpr int HROWS = TTILE + 2;    // 258 h rows actually consumed by conv
constexpr int HSTR = 36;            // ushort stride per h row (72B, 8B-aligned rows)
// SSTR=38 (R15): g-stride 152B == 24 mod 32 dwords -> staging writes 2-way (free).
constexpr int SSTR = 38;            // f32 stride of store-staging tile (152B)
constexpr int NBLK = NB * NJ * NTILES;  // 6784
constexpr int XSPAN = NBLK / 8;         // 848 (bijective XCD swizzle)
}

__constant__ int c_name_ids[NJ] = {
    0,1,2,3,4,1,2,3,4,5,6,7,8,9,10,11,12,13,14,15,16,14,15,16,14,15,16,
    14,15,16,14,15,16,10,11,12,13,14,15,16,14,15,16,14,15,16,14,15,16,
    14,15,16,17};

// Precomputed weight fragments: [name][ks|k][nt][hi/lo][lane]
__device__ short8_t g_linfrag[NN][2][2][2][64];   // 147 KB
__device__ short8_t g_convfrag[NN][3][2][2][64];  // 221 KB

__device__ __forceinline__ unsigned short f2bf(float f) {
  return __builtin_bit_cast(unsigned short, __float2bfloat16(f));
}
__device__ __forceinline__ float bf2f(unsigned short u) {
  return __bfloat162float(__builtin_bit_cast(__hip_bfloat16, u));
}

// slot map: slot(g,e) -> k = 4g + (e&3) + 16*(e>>2); used identically for A and B
// fragments, so any true HW k-map yields a correct dot product.

__global__ __launch_bounds__(64)
void prep_weights(const float* __restrict__ lin_w,
                  const float* __restrict__ conv_w)
{
  const int n = blockIdx.x;
  const int l = threadIdx.x;
  const int r = l & 15;
  const int g = l >> 4;
#pragma unroll
  for (int ks = 0; ks < 2; ++ks)
#pragma unroll
    for (int nt = 0; nt < 2; ++nt) {
      short8_t hi8, lo8;
#pragma unroll
      for (int e = 0; e < 8; ++e) {
        const int kk = 4 * g + (e & 3) + 16 * (e >> 2);
        const float w = lin_w[((size_t)n * 64 + ks * 32 + kk) * 32 + r + 16 * nt];
        const unsigned short h = f2bf(w);
        hi8[e] = (short)h;
        lo8[e] = (short)f2bf(w - bf2f(h));
      }
      g_linfrag[n][ks][nt][0][l] = hi8;
      g_linfrag[n][ks][nt][1][l] = lo8;
    }
#pragma unroll
  for (int k = 0; k < 3; ++k)
#pragma unroll
    for (int nt = 0; nt < 2; ++nt) {
      short8_t hi8, lo8;
#pragma unroll
      for (int e = 0; e < 8; ++e) {
        const int i = 4 * g + (e & 3) + 16 * (e >> 2);
        const float w = conv_w[(((size_t)n * 32 + r + 16 * nt) * 32 + i) * 3 + k];
        const unsigned short h = f2bf(w);
        hi8[e] = (short)h;
        lo8[e] = (short)f2bf(w - bf2f(h));
      }
      g_convfrag[n][k][nt][0][l] = hi8;
      g_convfrag[n][k][nt][1][l] = lo8;
    }
}

// R19 = R16 structure with 512-thread blocks (8 waves, tile stride 8).
// Rationale: R16 counters (VALUBusy 22.5, MfmaUtil 13, Occ 42%) show waves
// ~90% stalled in per-wave latency chains with only 16 waves/CU to hide them.
// 8-wave blocks at LDS 51.3KB -> 3 blocks/CU = 24 waves/CU (75% cap).
// Everything else is R16 verbatim:
//   - LDS-DMA feat staging + source-side XOR swizzle (rule #21)
//   - phase separation (lin weights and conv weights NEVER live together --
//     R14/R18 proved fusing them spills: WRITE_SIZE 217 -> 485/848 MB)
//   - SSTR=38 staging bank fix, RTZ hi/lo cvt, NT out stores
// __launch_bounds__(512,6): targets ~85 VGPRs >= the ~52 needed; no spill.
__global__ __launch_bounds__(512, 6)
void fused_rcb_mfma(const float* __restrict__ x,
                    const float* __restrict__ lin_b,
                    const float* __restrict__ conv_b,
                    float* __restrict__ out)
{
  __shared__ __align__(16) unsigned short s_hi[HROWS * HSTR];  // 18.6 KB
  __shared__ __align__(16) char s_feat[NWAVES][4096];          // 32 KB: feat stage (lin) / store stage (conv)

  const int raw = blockIdx.x;
  const int bid = (raw % 8) * XSPAN + (raw / 8);   // bijective XCD swizzle
  const int j    = bid % NJ;
  const int tile = (bid / NJ) % NTILES;
  const int b    = bid / (NJ * NTILES);
  const int nid  = c_name_ids[j];
  const int jp   = (j > 0) ? (j - 1) : 0;
  const int t0   = tile * TTILE;

  const int tid = threadIdx.x;
  const int wv = tid >> 6;        // wave 0..7
  const int l  = tid & 63;
  const int r  = l & 15;          // M/N index within fragment
  const int g  = l >> 4;          // k-slot group

  char* featc = s_feat[wv];       // wave-private

  const float* xj_base = x + ((size_t)b * T * NJ + j) * 32;
  const float* xp_base = x + ((size_t)b * T * NJ + jp) * 32;

  // ---- linear weight fragments: coalesced 16B/lane loads from prep table ----
  short8_t blh[2][2], bll[2][2];
#pragma unroll
  for (int ks = 0; ks < 2; ++ks)
#pragma unroll
    for (int nt = 0; nt < 2; ++nt) {
      blh[ks][nt] = g_linfrag[nid][ks][nt][0][l];
      bll[ks][nt] = g_linfrag[nid][ks][nt][1][l];
    }
  const float lb0 = lin_b[nid * 32 + r];
  const float lb1 = lin_b[nid * 32 + r + 16];

  // Issue the 4 LDS-DMA loads for m-tile mt: 2 j x 2 groups of 8 rows, each
  // instruction a contiguous 1KB (8 full lines). Global source byte is
  // inverse-XOR-swizzled so LDS holds the swizzled layout (rule #21).
  auto issue_feat = [&](int mt) {
#pragma unroll
    for (int j2 = 0; j2 < 2; ++j2) {
      const float* jb = j2 ? xp_base : xj_base;
#pragma unroll
      for (int i = 0; i < 2; ++i) {
        const int row = i * 8 + (l >> 3);
        int t = t0 + mt * 16 + row - 1;       // reflect padding in time
        if (t < 0) t = -t;
        if (t > T - 1) t = 2 * (T - 1) - t;
        const char* src = reinterpret_cast<const char*>(jb + (size_t)t * (NJ * 32))
                          + (((l & 7) * 16) ^ ((row & 7) << 4));
        __builtin_amdgcn_global_load_lds(
            (const __attribute__((address_space(1))) unsigned int*)src,
            (__attribute__((address_space(3))) unsigned int*)(&s_feat[wv][j2 * 2048 + i * 1024]),
            16, 0, 0);
      }
    }
  };

  // ---------------- linear phase: h = relu(feat @ W + b) ----------------
  issue_feat(wv);
  for (int mt = wv; mt < MT_LIN; mt += NWAVES) {
    VM_FENCE();   // feat[mt] fully landed in LDS (LDS-DMA tracked by vmcnt)

    // Fragment ds_reads first; cvt deferred until after next DMA is issued so
    // the DMA overlaps the cvt chain AND the MFMA block.
    f32x4 a0[2], a1[2];
#pragma unroll
    for (int ks = 0; ks < 2; ++ks) {
      const char* fw = featc + ks * 2048 + r * 128;
      a0[ks] = *reinterpret_cast<const f32x4*>(fw + ((16 * g) ^ ((r & 7) << 4)));
      a1[ks] = *reinterpret_cast<const f32x4*>(fw + ((64 + 16 * g) ^ ((r & 7) << 4)));
    }
    WAVE_FENCE();                       // feat reads retired -> buffer reusable
    if (mt + NWAVES < MT_LIN) issue_feat(mt + NWAVES);   // DMA overlaps cvt + MFMA below

    short8_t ah[2], al[2];
#pragma unroll
    for (int ks = 0; ks < 2; ++ks) {
#pragma unroll
      for (int e = 0; e < 8; ++e) {
        const float f = (e < 4) ? a0[ks][e] : a1[ks][e - 4];
        const uint32_t bi = __builtin_bit_cast(uint32_t, f);
        ah[ks][e] = (short)(unsigned short)(bi >> 16);                    // hi = RTZ top16
        const float lo = f - __builtin_bit_cast(float, bi & 0xffff0000u); // exact residual
        al[ks][e] = (short)(unsigned short)(__builtin_bit_cast(uint32_t, lo) >> 16); // RTZ
      }
    }

#pragma unroll
    for (int nt = 0; nt < 2; ++nt) {
      const float lb = nt ? lb1 : lb0;
      f32x4 acc = {lb, lb, lb, lb};
#pragma unroll
      for (int ks = 0; ks < 2; ++ks) {
        acc = __builtin_amdgcn_mfma_f32_16x16x32_bf16(ah[ks], blh[ks][nt], acc, 0, 0, 0);
        acc = __builtin_amdgcn_mfma_f32_16x16x32_bf16(al[ks], blh[ks][nt], acc, 0, 0, 0);
        acc = __builtin_amdgcn_mfma_f32_16x16x32_bf16(ah[ks], bll[ks][nt], acc, 0, 0, 0);
      }
      // C/D layout (m89): row = 4g+q, col = r
#pragma unroll
      for (int q = 0; q < 4; ++q) {
        const int hrow = mt * 16 + 4 * g + q;
        if (hrow < HROWS)   // only mt=16 tail rows are out of range
          s_hi[hrow * HSTR + r + 16 * nt] = f2bf(fmaxf(acc[q], 0.0f));
      }
    }
  }

  // ---- conv weight fragments: issue BEFORE the barrier so the global-load
  // latency hides under the slowest wave's lin tail ----
  short8_t bch[3][2], bcl[3][2];
#pragma unroll
  for (int k = 0; k < 3; ++k)
#pragma unroll
    for (int nt = 0; nt < 2; ++nt) {
      bch[k][nt] = g_convfrag[nid][k][nt][0][l];
      bcl[k][nt] = g_convfrag[nid][k][nt][1][l];
    }
  const float cb0 = conv_b[nid * 32 + r];
  const float cb1 = conv_b[nid * 32 + r + 16];

  __syncthreads();

  float* st = reinterpret_cast<float*>(featc);   // alias: feat buffer dead in conv

  // ---------------- conv phase: y[t] = sum_k h[t+k-1] @ cw[k] + cb ----------------
  for (int mt = wv; mt < MT_CNV; mt += NWAVES) {
    const int m0 = mt * 16;
    short8_t ah[3];
#pragma unroll
    for (int k = 0; k < 3; ++k) {
      const int arow = m0 + r + k;
      const ushort4a u0 = *reinterpret_cast<const ushort4a*>(&s_hi[arow * HSTR + 4 * g]);
      const ushort4a u1 = *reinterpret_cast<const ushort4a*>(&s_hi[arow * HSTR + 16 + 4 * g]);
      short8_t hi8;
#pragma unroll
      for (int e = 0; e < 4; ++e) {
        hi8[e] = (short)u0[e];
        hi8[e + 4] = (short)u1[e];
      }
      ah[k] = hi8;
    }

    f32x4 accv[2];
#pragma unroll
    for (int nt = 0; nt < 2; ++nt) {
      const float cb = nt ? cb1 : cb0;
      f32x4 acc = {cb, cb, cb, cb};
#pragma unroll
      for (int k = 0; k < 3; ++k) {
        acc = __builtin_amdgcn_mfma_f32_16x16x32_bf16(ah[k], bch[k][nt], acc, 0, 0, 0);
        acc = __builtin_amdgcn_mfma_f32_16x16x32_bf16(ah[k], bcl[k][nt], acc, 0, 0, 0);
      }
      accv[nt] = acc;
    }

    // ---- wide-store epilogue: transpose acc through wave-private LDS ----
    WAVE_FENCE();   // WAR: previous m-tile's staging reads retired
#pragma unroll
    for (int nt = 0; nt < 2; ++nt)
#pragma unroll
      for (int q = 0; q < 4; ++q)
        st[(4 * g + q) * SSTR + r + 16 * nt] = accv[nt][q];
    WAVE_FENCE();   // RAW: staging writes visible to transposed reads

#pragma unroll
    for (int h2 = 0; h2 < 2; ++h2) {
      const int row = h2 * 8 + (l >> 3);          // 8-lane groups read one row
      const float* rp = st + row * SSTR + (l & 7) * 4;
      const f32x2 rd0 = *reinterpret_cast<const f32x2*>(rp);      // 8B reads keep
      const f32x2 rd1 = *reinterpret_cast<const f32x2*>(rp + 2);  // odd rows aligned
      f32x4 rd;
      rd[0] = rd0[0]; rd[1] = rd0[1]; rd[2] = rd1[0]; rd[3] = rd1[1];
      const int t = t0 + m0 + row;
      // Nontemporal: out is write-once; do not evict the L2-resident x columns.
      __builtin_nontemporal_store(rd, reinterpret_cast<f32x4*>(
          out + ((size_t)(b * T + t) * NJ + j) * 32 + (l & 7) * 4));
    }
  }
}

extern "C" void kernel_launch(void* const* d_in, const int* in_sizes, int n_in,
                              void* d_out, int out_size, void* d_ws, size_t ws_size,
                              hipStream_t stream) {
  const float* x      = (const float*)d_in[0];
  const float* lin_w  = (const float*)d_in[1];
  const float* lin_b  = (const float*)d_in[2];
  const float* conv_w = (const float*)d_in[3];
  const float* conv_b = (const float*)d_in[4];
  float* out = (float*)d_out;

  prep_weights<<<dim3(NN), 64, 0, stream>>>(lin_w, conv_w);
  fused_rcb_mfma<<<dim3(NBLK), 512, 0, stream>>>(x, lin_b, conv_b, out);
}

// Round 8
// 90.840 us; speedup vs baseline: 4.3650x; 1.7304x over previous
//
#include <hip/hip_runtime.h>
#include <hip/hip_bf16.h>
#include <cstddef>
#include <cstdint>

typedef __attribute__((ext_vector_type(8))) short short8_t;   // 8 bf16 (4 VGPRs)
typedef __attribute__((ext_vector_type(4))) float f32x4;
typedef __attribute__((ext_vector_type(2))) float f32x2;
typedef unsigned short ushort4a __attribute__((ext_vector_type(4))); // 8B

// Per-wave fences: forbid compiler motion of memory ops and drain the HW
// queue. Cross-lane LDS deps and LDS-DMA writes are invisible to per-thread
// dependence analysis.
#define WAVE_FENCE()                                        \
  do {                                                      \
    asm volatile("s_waitcnt lgkmcnt(0)" ::: "memory");      \
    __builtin_amdgcn_sched_barrier(0);                      \
  } while (0)
#define VM_FENCE()                                          \
  do {                                                      \
    asm volatile("s_waitcnt vmcnt(0)" ::: "memory");        \
    __builtin_amdgcn_sched_barrier(0);                      \
  } while (0)

namespace {
constexpr int T = 2048;
constexpr int NB = 16;
constexpr int NJ = 53;
constexpr int NN = 18;              // names
constexpr int TTILE = 256;          // R16: per-block tax amortization; NT stores keep L2 reuse
constexpr int NTILES = T / TTILE;   // 8
constexpr int NWAVES = 8;           // 512-thread blocks -> 8 waves
constexpr int MT_LIN = 17;          // ceil(258/16) m-tiles for linear phase
constexpr int MT_CNV = 16;          // conv m-tiles
constexpr int HROWS = TTILE + 2;    // 258 h rows actually consumed by conv
constexpr int HSTR = 36;            // ushort stride per h row (72B, 8B-aligned rows)
// SSTR=38 (R15): g-stride 152B == 24 mod 32 dwords -> staging writes 2-way (free).
constexpr int SSTR = 38;            // f32 stride of store-staging tile (152B)
constexpr int NBLK = NB * NJ * NTILES;  // 6784
constexpr int XSPAN = NBLK / 8;         // 848 (bijective XCD swizzle)
}

__constant__ int c_name_ids[NJ] = {
    0,1,2,3,4,1,2,3,4,5,6,7,8,9,10,11,12,13,14,15,16,14,15,16,14,15,16,
    14,15,16,14,15,16,10,11,12,13,14,15,16,14,15,16,14,15,16,14,15,16,
    14,15,16,17};

// Precomputed weight fragments: [name][ks|k][nt][hi/lo][lane]
__device__ short8_t g_linfrag[NN][2][2][2][64];   // 147 KB
__device__ short8_t g_convfrag[NN][3][2][2][64];  // 221 KB

__device__ __forceinline__ unsigned short f2bf(float f) {
  return __builtin_bit_cast(unsigned short, __float2bfloat16(f));
}
__device__ __forceinline__ float bf2f(unsigned short u) {
  return __bfloat162float(__builtin_bit_cast(__hip_bfloat16, u));
}

// slot map: slot(g,e) -> k = 4g + (e&3) + 16*(e>>2); used identically for A and B
// fragments, so any true HW k-map yields a correct dot product.

__global__ __launch_bounds__(64)
void prep_weights(const float* __restrict__ lin_w,
                  const float* __restrict__ conv_w)
{
  const int n = blockIdx.x;
  const int l = threadIdx.x;
  const int r = l & 15;
  const int g = l >> 4;
#pragma unroll
  for (int ks = 0; ks < 2; ++ks)
#pragma unroll
    for (int nt = 0; nt < 2; ++nt) {
      short8_t hi8, lo8;
#pragma unroll
      for (int e = 0; e < 8; ++e) {
        const int kk = 4 * g + (e & 3) + 16 * (e >> 2);
        const float w = lin_w[((size_t)n * 64 + ks * 32 + kk) * 32 + r + 16 * nt];
        const unsigned short h = f2bf(w);
        hi8[e] = (short)h;
        lo8[e] = (short)f2bf(w - bf2f(h));
      }
      g_linfrag[n][ks][nt][0][l] = hi8;
      g_linfrag[n][ks][nt][1][l] = lo8;
    }
#pragma unroll
  for (int k = 0; k < 3; ++k)
#pragma unroll
    for (int nt = 0; nt < 2; ++nt) {
      short8_t hi8, lo8;
#pragma unroll
      for (int e = 0; e < 8; ++e) {
        const int i = 4 * g + (e & 3) + 16 * (e >> 2);
        const float w = conv_w[(((size_t)n * 32 + r + 16 * nt) * 32 + i) * 3 + k];
        const unsigned short h = f2bf(w);
        hi8[e] = (short)h;
        lo8[e] = (short)f2bf(w - bf2f(h));
      }
      g_convfrag[n][k][nt][0][l] = hi8;
      g_convfrag[n][k][nt][1][l] = lo8;
    }
}

// R20 = R19 with the launch-bounds trap removed. __launch_bounds__(512, 4):
// the 2nd arg sets the ALLOCATOR BUDGET (512/4 = 128 VGPR -- same budget as
// R16's proven (256,4) which gave VGPR=52, zero spill). Runtime occupancy is
// then capped by actual LDS: 51.7KB -> 3 blocks/CU x 8 waves = 24 waves/CU
// (75%), vs R16's 42%. (512,6) [R19] made the allocator target 40 VGPR for
// ~52 live values -> scratch spills (+244MB HBM writes). Third spill incident
// from this knob: (256,7)->36 [R14], (512,6)->40 [R19].
// Everything else is R16/R19 verbatim:
//   - LDS-DMA feat staging + source-side XOR swizzle (rule #21)
//   - phase separation (lin/conv weights never co-live: R14/R18 spill proof)
//   - SSTR=38 staging bank fix, RTZ hi/lo cvt, NT out stores
__global__ __launch_bounds__(512, 4)
void fused_rcb_mfma(const float* __restrict__ x,
                    const float* __restrict__ lin_b,
                    const float* __restrict__ conv_b,
                    float* __restrict__ out)
{
  __shared__ __align__(16) unsigned short s_hi[HROWS * HSTR];  // 18.6 KB
  __shared__ __align__(16) char s_feat[NWAVES][4096];          // 32 KB: feat stage (lin) / store stage (conv)

  const int raw = blockIdx.x;
  const int bid = (raw % 8) * XSPAN + (raw / 8);   // bijective XCD swizzle
  const int j    = bid % NJ;
  const int tile = (bid / NJ) % NTILES;
  const int b    = bid / (NJ * NTILES);
  const int nid  = c_name_ids[j];
  const int jp   = (j > 0) ? (j - 1) : 0;
  const int t0   = tile * TTILE;

  const int tid = threadIdx.x;
  const int wv = tid >> 6;        // wave 0..7
  const int l  = tid & 63;
  const int r  = l & 15;          // M/N index within fragment
  const int g  = l >> 4;          // k-slot group

  char* featc = s_feat[wv];       // wave-private

  const float* xj_base = x + ((size_t)b * T * NJ + j) * 32;
  const float* xp_base = x + ((size_t)b * T * NJ + jp) * 32;

  // ---- linear weight fragments: coalesced 16B/lane loads from prep table ----
  short8_t blh[2][2], bll[2][2];
#pragma unroll
  for (int ks = 0; ks < 2; ++ks)
#pragma unroll
    for (int nt = 0; nt < 2; ++nt) {
      blh[ks][nt] = g_linfrag[nid][ks][nt][0][l];
      bll[ks][nt] = g_linfrag[nid][ks][nt][1][l];
    }
  const float lb0 = lin_b[nid * 32 + r];
  const float lb1 = lin_b[nid * 32 + r + 16];

  // Issue the 4 LDS-DMA loads for m-tile mt: 2 j x 2 groups of 8 rows, each
  // instruction a contiguous 1KB (8 full lines). Global source byte is
  // inverse-XOR-swizzled so LDS holds the swizzled layout (rule #21).
  auto issue_feat = [&](int mt) {
#pragma unroll
    for (int j2 = 0; j2 < 2; ++j2) {
      const float* jb = j2 ? xp_base : xj_base;
#pragma unroll
      for (int i = 0; i < 2; ++i) {
        const int row = i * 8 + (l >> 3);
        int t = t0 + mt * 16 + row - 1;       // reflect padding in time
        if (t < 0) t = -t;
        if (t > T - 1) t = 2 * (T - 1) - t;
        const char* src = reinterpret_cast<const char*>(jb + (size_t)t * (NJ * 32))
                          + (((l & 7) * 16) ^ ((row & 7) << 4));
        __builtin_amdgcn_global_load_lds(
            (const __attribute__((address_space(1))) unsigned int*)src,
            (__attribute__((address_space(3))) unsigned int*)(&s_feat[wv][j2 * 2048 + i * 1024]),
            16, 0, 0);
      }
    }
  };

  // ---------------- linear phase: h = relu(feat @ W + b) ----------------
  issue_feat(wv);
  for (int mt = wv; mt < MT_LIN; mt += NWAVES) {
    VM_FENCE();   // feat[mt] fully landed in LDS (LDS-DMA tracked by vmcnt)

    // Fragment ds_reads first; cvt deferred until after next DMA is issued so
    // the DMA overlaps the cvt chain AND the MFMA block.
    f32x4 a0[2], a1[2];
#pragma unroll
    for (int ks = 0; ks < 2; ++ks) {
      const char* fw = featc + ks * 2048 + r * 128;
      a0[ks] = *reinterpret_cast<const f32x4*>(fw + ((16 * g) ^ ((r & 7) << 4)));
      a1[ks] = *reinterpret_cast<const f32x4*>(fw + ((64 + 16 * g) ^ ((r & 7) << 4)));
    }
    WAVE_FENCE();                       // feat reads retired -> buffer reusable
    if (mt + NWAVES < MT_LIN) issue_feat(mt + NWAVES);   // DMA overlaps cvt + MFMA below

    short8_t ah[2], al[2];
#pragma unroll
    for (int ks = 0; ks < 2; ++ks) {
#pragma unroll
      for (int e = 0; e < 8; ++e) {
        const float f = (e < 4) ? a0[ks][e] : a1[ks][e - 4];
        const uint32_t bi = __builtin_bit_cast(uint32_t, f);
        ah[ks][e] = (short)(unsigned short)(bi >> 16);                    // hi = RTZ top16
        const float lo = f - __builtin_bit_cast(float, bi & 0xffff0000u); // exact residual
        al[ks][e] = (short)(unsigned short)(__builtin_bit_cast(uint32_t, lo) >> 16); // RTZ
      }
    }

#pragma unroll
    for (int nt = 0; nt < 2; ++nt) {
      const float lb = nt ? lb1 : lb0;
      f32x4 acc = {lb, lb, lb, lb};
#pragma unroll
      for (int ks = 0; ks < 2; ++ks) {
        acc = __builtin_amdgcn_mfma_f32_16x16x32_bf16(ah[ks], blh[ks][nt], acc, 0, 0, 0);
        acc = __builtin_amdgcn_mfma_f32_16x16x32_bf16(al[ks], blh[ks][nt], acc, 0, 0, 0);
        acc = __builtin_amdgcn_mfma_f32_16x16x32_bf16(ah[ks], bll[ks][nt], acc, 0, 0, 0);
      }
      // C/D layout (m89): row = 4g+q, col = r
#pragma unroll
      for (int q = 0; q < 4; ++q) {
        const int hrow = mt * 16 + 4 * g + q;
        if (hrow < HROWS)   // only mt=16 tail rows are out of range
          s_hi[hrow * HSTR + r + 16 * nt] = f2bf(fmaxf(acc[q], 0.0f));
      }
    }
  }

  // ---- conv weight fragments: issue BEFORE the barrier so the global-load
  // latency hides under the slowest wave's lin tail ----
  short8_t bch[3][2], bcl[3][2];
#pragma unroll
  for (int k = 0; k < 3; ++k)
#pragma unroll
    for (int nt = 0; nt < 2; ++nt) {
      bch[k][nt] = g_convfrag[nid][k][nt][0][l];
      bcl[k][nt] = g_convfrag[nid][k][nt][1][l];
    }
  const float cb0 = conv_b[nid * 32 + r];
  const float cb1 = conv_b[nid * 32 + r + 16];

  __syncthreads();

  float* st = reinterpret_cast<float*>(featc);   // alias: feat buffer dead in conv

  // ---------------- conv phase: y[t] = sum_k h[t+k-1] @ cw[k] + cb ----------------
  for (int mt = wv; mt < MT_CNV; mt += NWAVES) {
    const int m0 = mt * 16;
    short8_t ah[3];
#pragma unroll
    for (int k = 0; k < 3; ++k) {
      const int arow = m0 + r + k;
      const ushort4a u0 = *reinterpret_cast<const ushort4a*>(&s_hi[arow * HSTR + 4 * g]);
      const ushort4a u1 = *reinterpret_cast<const ushort4a*>(&s_hi[arow * HSTR + 16 + 4 * g]);
      short8_t hi8;
#pragma unroll
      for (int e = 0; e < 4; ++e) {
        hi8[e] = (short)u0[e];
        hi8[e + 4] = (short)u1[e];
      }
      ah[k] = hi8;
    }

    f32x4 accv[2];
#pragma unroll
    for (int nt = 0; nt < 2; ++nt) {
      const float cb = nt ? cb1 : cb0;
      f32x4 acc = {cb, cb, cb, cb};
#pragma unroll
      for (int k = 0; k < 3; ++k) {
        acc = __builtin_amdgcn_mfma_f32_16x16x32_bf16(ah[k], bch[k][nt], acc, 0, 0, 0);
        acc = __builtin_amdgcn_mfma_f32_16x16x32_bf16(ah[k], bcl[k][nt], acc, 0, 0, 0);
      }
      accv[nt] = acc;
    }

    // ---- wide-store epilogue: transpose acc through wave-private LDS ----
    WAVE_FENCE();   // WAR: previous m-tile's staging reads retired
#pragma unroll
    for (int nt = 0; nt < 2; ++nt)
#pragma unroll
      for (int q = 0; q < 4; ++q)
        st[(4 * g + q) * SSTR + r + 16 * nt] = accv[nt][q];
    WAVE_FENCE();   // RAW: staging writes visible to transposed reads

#pragma unroll
    for (int h2 = 0; h2 < 2; ++h2) {
      const int row = h2 * 8 + (l >> 3);          // 8-lane groups read one row
      const float* rp = st + row * SSTR + (l & 7) * 4;
      const f32x2 rd0 = *reinterpret_cast<const f32x2*>(rp);      // 8B reads keep
      const f32x2 rd1 = *reinterpret_cast<const f32x2*>(rp + 2);  // odd rows aligned
      f32x4 rd;
      rd[0] = rd0[0]; rd[1] = rd0[1]; rd[2] = rd1[0]; rd[3] = rd1[1];
      const int t = t0 + m0 + row;
      // Nontemporal: out is write-once; do not evict the L2-resident x columns.
      __builtin_nontemporal_store(rd, reinterpret_cast<f32x4*>(
          out + ((size_t)(b * T + t) * NJ + j) * 32 + (l & 7) * 4));
    }
  }
}

extern "C" void kernel_launch(void* const* d_in, const int* in_sizes, int n_in,
                              void* d_out, int out_size, void* d_ws, size_t ws_size,
                              hipStream_t stream) {
  const float* x      = (const float*)d_in[0];
  const float* lin_w  = (const float*)d_in[1];
  const float* lin_b  = (const float*)d_in[2];
  const float* conv_w = (const float*)d_in[3];
  const float* conv_b = (const float*)d_in[4];
  float* out = (float*)d_out;

  prep_weights<<<dim3(NN), 64, 0, stream>>>(lin_w, conv_w);
  fused_rcb_mfma<<<dim3(NBLK), 512, 0, stream>>>(x, lin_b, conv_b, out);
}

// Round 9
// 77.054 us; speedup vs baseline: 5.1461x; 1.1789x over previous
//
#include <hip/hip_runtime.h>
#include <hip/hip_bf16.h>
#include <cstddef>
#include <cstdint>

typedef __attribute__((ext_vector_type(8))) short short8_t;   // 8 bf16 (4 VGPRs)
typedef __attribute__((ext_vector_type(4))) float f32x4;
typedef __attribute__((ext_vector_type(2))) float f32x2;
typedef unsigned short ushort4a __attribute__((ext_vector_type(4))); // 8B

// Per-wave fences: forbid compiler motion of memory ops and drain the HW
// queue. Cross-lane LDS deps and LDS-DMA writes are invisible to per-thread
// dependence analysis.
#define WAVE_FENCE()                                        \
  do {                                                      \
    asm volatile("s_waitcnt lgkmcnt(0)" ::: "memory");      \
    __builtin_amdgcn_sched_barrier(0);                      \
  } while (0)
#define VM_FENCE()                                          \
  do {                                                      \
    asm volatile("s_waitcnt vmcnt(0)" ::: "memory");        \
    __builtin_amdgcn_sched_barrier(0);                      \
  } while (0)

namespace {
constexpr int T = 2048;
constexpr int NB = 16;
constexpr int NJ = 53;
constexpr int NN = 18;              // names
constexpr int TTILE = 256;          // R16: per-block tax amortization; NT stores keep L2 reuse
constexpr int NTILES = T / TTILE;   // 8
constexpr int MT_LIN = 17;          // ceil(258/16) m-tiles for linear phase
constexpr int MT_CNV = 16;          // conv m-tiles
constexpr int HROWS = TTILE + 2;    // 258 h rows actually consumed by conv
constexpr int HSTR = 36;            // ushort stride per h row (72B, 8B-aligned rows)
// SSTR=38 (R15): g-stride 152B == 24 mod 32 dwords -> staging writes 2-way (free).
constexpr int SSTR = 38;            // f32 stride of store-staging tile (152B)
constexpr int NBLK = NB * NJ * NTILES;  // 6784
constexpr int XSPAN = NBLK / 8;         // 848 (bijective XCD swizzle)
}

__constant__ int c_name_ids[NJ] = {
    0,1,2,3,4,1,2,3,4,5,6,7,8,9,10,11,12,13,14,15,16,14,15,16,14,15,16,
    14,15,16,14,15,16,10,11,12,13,14,15,16,14,15,16,14,15,16,14,15,16,
    14,15,16,17};

// Precomputed weight fragments: [name][ks|k][nt][hi/lo][lane]
__device__ short8_t g_linfrag[NN][2][2][2][64];   // 147 KB
__device__ short8_t g_convfrag[NN][3][2][2][64];  // 221 KB

__device__ __forceinline__ unsigned short f2bf(float f) {
  return __builtin_bit_cast(unsigned short, __float2bfloat16(f));
}
__device__ __forceinline__ float bf2f(unsigned short u) {
  return __bfloat162float(__builtin_bit_cast(__hip_bfloat16, u));
}

// slot map: slot(g,e) -> k = 4g + (e&3) + 16*(e>>2); used identically for A and B
// fragments, so any true HW k-map yields a correct dot product.

__global__ __launch_bounds__(64)
void prep_weights(const float* __restrict__ lin_w,
                  const float* __restrict__ conv_w)
{
  const int n = blockIdx.x;
  const int l = threadIdx.x;
  const int r = l & 15;
  const int g = l >> 4;
#pragma unroll
  for (int ks = 0; ks < 2; ++ks)
#pragma unroll
    for (int nt = 0; nt < 2; ++nt) {
      short8_t hi8, lo8;
#pragma unroll
      for (int e = 0; e < 8; ++e) {
        const int kk = 4 * g + (e & 3) + 16 * (e >> 2);
        const float w = lin_w[((size_t)n * 64 + ks * 32 + kk) * 32 + r + 16 * nt];
        const unsigned short h = f2bf(w);
        hi8[e] = (short)h;
        lo8[e] = (short)f2bf(w - bf2f(h));
      }
      g_linfrag[n][ks][nt][0][l] = hi8;
      g_linfrag[n][ks][nt][1][l] = lo8;
    }
#pragma unroll
  for (int k = 0; k < 3; ++k)
#pragma unroll
    for (int nt = 0; nt < 2; ++nt) {
      short8_t hi8, lo8;
#pragma unroll
      for (int e = 0; e < 8; ++e) {
        const int i = 4 * g + (e & 3) + 16 * (e >> 2);
        const float w = conv_w[(((size_t)n * 32 + r + 16 * nt) * 32 + i) * 3 + k];
        const unsigned short h = f2bf(w);
        hi8[e] = (short)h;
        lo8[e] = (short)f2bf(w - bf2f(h));
      }
      g_convfrag[n][k][nt][0][l] = hi8;
      g_convfrag[n][k][nt][1][l] = lo8;
    }
}

// R21 = R16 exactly (the proven best config: 256 thr, TTILE=256, (256,4))
// with the lin phase's INPUT-residual term dropped:
//   - cvt loop: only ah = top16(f) (1 shift+pack per elem; was ~6 ops for
//     ah/lo/al). The cvt chain was the largest measured pipe consumer
//     (VALUBusy 22.5% > MfmaUtil 12%) and sits serialized between VM_FENCE
//     and the MFMAs.
//   - lin MFMA: ah@blh + ah@bll (8/tile, was 12). Weight residual bll is
//     precomputed -- kept for free accuracy. Error added to h ~ the same
//     order as the bf16 h-storage rounding already tolerated; the conv
//     phase has ALWAYS dropped its input residual and passes.
// R17-R20 lessons baked in: LDS-DMA staging only (direct loads lose),
// 4-wave blocks (8-wave pinned at same 16 waves/CU by LDS granularity and
// doubled weight-prologue), phase separation (fusing weight sets spills).
__global__ __launch_bounds__(256, 4)
void fused_rcb_mfma(const float* __restrict__ x,
                    const float* __restrict__ lin_b,
                    const float* __restrict__ conv_b,
                    float* __restrict__ out)
{
  __shared__ __align__(16) unsigned short s_hi[HROWS * HSTR];  // 18.6 KB
  __shared__ __align__(16) char s_feat[4][4096];               // 16 KB: feat stage (lin) / store stage (conv)

  const int raw = blockIdx.x;
  const int bid = (raw % 8) * XSPAN + (raw / 8);   // bijective XCD swizzle
  const int j    = bid % NJ;
  const int tile = (bid / NJ) % NTILES;
  const int b    = bid / (NJ * NTILES);
  const int nid  = c_name_ids[j];
  const int jp   = (j > 0) ? (j - 1) : 0;
  const int t0   = tile * TTILE;

  const int tid = threadIdx.x;
  const int wv = tid >> 6;        // wave 0..3
  const int l  = tid & 63;
  const int r  = l & 15;          // M/N index within fragment
  const int g  = l >> 4;          // k-slot group

  char* featc = s_feat[wv];       // wave-private

  const float* xj_base = x + ((size_t)b * T * NJ + j) * 32;
  const float* xp_base = x + ((size_t)b * T * NJ + jp) * 32;

  // ---- linear weight fragments: coalesced 16B/lane loads from prep table ----
  short8_t blh[2][2], bll[2][2];
#pragma unroll
  for (int ks = 0; ks < 2; ++ks)
#pragma unroll
    for (int nt = 0; nt < 2; ++nt) {
      blh[ks][nt] = g_linfrag[nid][ks][nt][0][l];
      bll[ks][nt] = g_linfrag[nid][ks][nt][1][l];
    }
  const float lb0 = lin_b[nid * 32 + r];
  const float lb1 = lin_b[nid * 32 + r + 16];

  // Issue the 4 LDS-DMA loads for m-tile mt: 2 j x 2 groups of 8 rows, each
  // instruction a contiguous 1KB (8 full lines). Global source byte is
  // inverse-XOR-swizzled so LDS holds the swizzled layout (rule #21).
  auto issue_feat = [&](int mt) {
#pragma unroll
    for (int j2 = 0; j2 < 2; ++j2) {
      const float* jb = j2 ? xp_base : xj_base;
#pragma unroll
      for (int i = 0; i < 2; ++i) {
        const int row = i * 8 + (l >> 3);
        int t = t0 + mt * 16 + row - 1;       // reflect padding in time
        if (t < 0) t = -t;
        if (t > T - 1) t = 2 * (T - 1) - t;
        const char* src = reinterpret_cast<const char*>(jb + (size_t)t * (NJ * 32))
                          + (((l & 7) * 16) ^ ((row & 7) << 4));
        __builtin_amdgcn_global_load_lds(
            (const __attribute__((address_space(1))) unsigned int*)src,
            (__attribute__((address_space(3))) unsigned int*)(&s_feat[wv][j2 * 2048 + i * 1024]),
            16, 0, 0);
      }
    }
  };

  // ---------------- linear phase: h = relu(feat @ W + b) ----------------
  issue_feat(wv);
  for (int mt = wv; mt < MT_LIN; mt += 4) {
    VM_FENCE();   // feat[mt] fully landed in LDS (LDS-DMA tracked by vmcnt)

    // Fragment ds_reads first; cvt deferred until after next DMA is issued so
    // the DMA overlaps the cvt chain AND the MFMA block.
    f32x4 a0[2], a1[2];
#pragma unroll
    for (int ks = 0; ks < 2; ++ks) {
      const char* fw = featc + ks * 2048 + r * 128;
      a0[ks] = *reinterpret_cast<const f32x4*>(fw + ((16 * g) ^ ((r & 7) << 4)));
      a1[ks] = *reinterpret_cast<const f32x4*>(fw + ((64 + 16 * g) ^ ((r & 7) << 4)));
    }
    WAVE_FENCE();                       // feat reads retired -> buffer reusable
    if (mt + 4 < MT_LIN) issue_feat(mt + 4);   // DMA overlaps cvt + MFMA below

    // R21: input hi-part only (RTZ top16). Residual al dropped -- see header.
    short8_t ah[2];
#pragma unroll
    for (int ks = 0; ks < 2; ++ks) {
#pragma unroll
      for (int e = 0; e < 8; ++e) {
        const float f = (e < 4) ? a0[ks][e] : a1[ks][e - 4];
        ah[ks][e] = (short)(unsigned short)(__builtin_bit_cast(uint32_t, f) >> 16);
      }
    }

#pragma unroll
    for (int nt = 0; nt < 2; ++nt) {
      const float lb = nt ? lb1 : lb0;
      f32x4 acc = {lb, lb, lb, lb};
#pragma unroll
      for (int ks = 0; ks < 2; ++ks) {
        acc = __builtin_amdgcn_mfma_f32_16x16x32_bf16(ah[ks], blh[ks][nt], acc, 0, 0, 0);
        acc = __builtin_amdgcn_mfma_f32_16x16x32_bf16(ah[ks], bll[ks][nt], acc, 0, 0, 0);
      }
      // C/D layout (m89): row = 4g+q, col = r
#pragma unroll
      for (int q = 0; q < 4; ++q) {
        const int hrow = mt * 16 + 4 * g + q;
        if (hrow < HROWS)   // only mt=16 tail rows are out of range
          s_hi[hrow * HSTR + r + 16 * nt] = f2bf(fmaxf(acc[q], 0.0f));
      }
    }
  }

  // ---- conv weight fragments: issue BEFORE the barrier so the global-load
  // latency hides under the slowest wave's lin tail ----
  short8_t bch[3][2], bcl[3][2];
#pragma unroll
  for (int k = 0; k < 3; ++k)
#pragma unroll
    for (int nt = 0; nt < 2; ++nt) {
      bch[k][nt] = g_convfrag[nid][k][nt][0][l];
      bcl[k][nt] = g_convfrag[nid][k][nt][1][l];
    }
  const float cb0 = conv_b[nid * 32 + r];
  const float cb1 = conv_b[nid * 32 + r + 16];

  __syncthreads();

  float* st = reinterpret_cast<float*>(featc);   // alias: feat buffer dead in conv

  // ---------------- conv phase: y[t] = sum_k h[t+k-1] @ cw[k] + cb ----------------
  for (int mt = wv; mt < MT_CNV; mt += 4) {
    const int m0 = mt * 16;
    short8_t ah[3];
#pragma unroll
    for (int k = 0; k < 3; ++k) {
      const int arow = m0 + r + k;
      const ushort4a u0 = *reinterpret_cast<const ushort4a*>(&s_hi[arow * HSTR + 4 * g]);
      const ushort4a u1 = *reinterpret_cast<const ushort4a*>(&s_hi[arow * HSTR + 16 + 4 * g]);
      short8_t hi8;
#pragma unroll
      for (int e = 0; e < 4; ++e) {
        hi8[e] = (short)u0[e];
        hi8[e + 4] = (short)u1[e];
      }
      ah[k] = hi8;
    }

    f32x4 accv[2];
#pragma unroll
    for (int nt = 0; nt < 2; ++nt) {
      const float cb = nt ? cb1 : cb0;
      f32x4 acc = {cb, cb, cb, cb};
#pragma unroll
      for (int k = 0; k < 3; ++k) {
        acc = __builtin_amdgcn_mfma_f32_16x16x32_bf16(ah[k], bch[k][nt], acc, 0, 0, 0);
        acc = __builtin_amdgcn_mfma_f32_16x16x32_bf16(ah[k], bcl[k][nt], acc, 0, 0, 0);
      }
      accv[nt] = acc;
    }

    // ---- wide-store epilogue: transpose acc through wave-private LDS ----
    WAVE_FENCE();   // WAR: previous m-tile's staging reads retired
#pragma unroll
    for (int nt = 0; nt < 2; ++nt)
#pragma unroll
      for (int q = 0; q < 4; ++q)
        st[(4 * g + q) * SSTR + r + 16 * nt] = accv[nt][q];
    WAVE_FENCE();   // RAW: staging writes visible to transposed reads

#pragma unroll
    for (int h2 = 0; h2 < 2; ++h2) {
      const int row = h2 * 8 + (l >> 3);          // 8-lane groups read one row
      const float* rp = st + row * SSTR + (l & 7) * 4;
      const f32x2 rd0 = *reinterpret_cast<const f32x2*>(rp);      // 8B reads keep
      const f32x2 rd1 = *reinterpret_cast<const f32x2*>(rp + 2);  // odd rows aligned
      f32x4 rd;
      rd[0] = rd0[0]; rd[1] = rd0[1]; rd[2] = rd1[0]; rd[3] = rd1[1];
      const int t = t0 + m0 + row;
      // Nontemporal: out is write-once; do not evict the L2-resident x columns.
      __builtin_nontemporal_store(rd, reinterpret_cast<f32x4*>(
          out + ((size_t)(b * T + t) * NJ + j) * 32 + (l & 7) * 4));
    }
  }
}

extern "C" void kernel_launch(void* const* d_in, const int* in_sizes, int n_in,
                              void* d_out, int out_size, void* d_ws, size_t ws_size,
                              hipStream_t stream) {
  const float* x      = (const float*)d_in[0];
  const float* lin_w  = (const float*)d_in[1];
  const float* lin_b  = (const float*)d_in[2];
  const float* conv_w = (const float*)d_in[3];
  const float* conv_b = (const float*)d_in[4];
  float* out = (float*)d_out;

  prep_weights<<<dim3(NN), 64, 0, stream>>>(lin_w, conv_w);
  fused_rcb_mfma<<<dim3(NBLK), 256, 0, stream>>>(x, lin_b, conv_b, out);
}